// Round 15
// baseline (476.010 us; speedup 1.0000x reference)
//
#include <hip/hip_runtime.h>
#include <stdint.h>

#define BATCH  65536
#define IN_DIM 1024
#define MASKED 512
#define HIDDEN 1024

typedef unsigned short u16;
typedef __bf16 bf16x8 __attribute__((ext_vector_type(8)));
typedef float  f32x4  __attribute__((ext_vector_type(4)));

typedef __attribute__((address_space(1))) void gvoid;
typedef __attribute__((address_space(3))) void lvoid;

__device__ __forceinline__ u16 f32_to_bf16(float f) {
    union { float f; uint32_t u; } v; v.f = f;
    uint32_t r = v.u + 0x7FFFu + ((v.u >> 16) & 1u);   // round-to-nearest-even
    return (u16)(r >> 16);
}

// ---------------------------------------------------------------------------
// prep + weight-convert merged into ONE dispatch (saves launch gaps).
// blocks [0, 32768):     x (BATCH x IN_DIM f32) -> xm (BATCH x MASKED bf16)
// blocks [32768, 34816): W1/W2/W3 (K x N f32) -> Wt (N x K bf16), 32x32 tiles
// ---------------------------------------------------------------------------
__global__ void prep_all(const float* __restrict__ x, u16* __restrict__ xm,
                         const float* __restrict__ W1, const float* __restrict__ W2,
                         const float* __restrict__ W3,
                         u16* __restrict__ W1t, u16* __restrict__ W2t,
                         u16* __restrict__ W3t) {
    __shared__ float t[32][33];
    int bid = blockIdx.x;
    if (bid < 32768) {
        // ---- prep: even-column extract + bf16 ----
        int idx = bid * blockDim.x + threadIdx.x;
        const float4* xv = reinterpret_cast<const float4*>(x);
        float4 v0 = xv[idx * 2];
        float4 v1 = xv[idx * 2 + 1];
        ushort4 o;
        o.x = f32_to_bf16(v0.x);
        o.y = f32_to_bf16(v0.z);
        o.z = f32_to_bf16(v1.x);
        o.w = f32_to_bf16(v1.z);
        reinterpret_cast<ushort4*>(xm)[idx] = o;
        return;
    }
    bid -= 32768;
    const float* W; u16* Wt; int K, N;
    if (bid < 512)       { W = W1; Wt = W1t; K = 512;  N = 1024; }
    else if (bid < 1536) { W = W2; Wt = W2t; K = 1024; N = 1024; bid -= 512; }
    else                 { W = W3; Wt = W3t; K = 1024; N = 512;  bid -= 1536; }
    const int nbk = K / 32;
    const int bk = bid % nbk;
    const int bn = bid / nbk;
    const int tx = threadIdx.x & 31;
    const int ty = threadIdx.x >> 5;   // 0..7
    const int k0 = bk * 32, n0 = bn * 32;
    #pragma unroll
    for (int i = 0; i < 4; ++i)
        t[ty + i * 8][tx] = W[(int64_t)(k0 + ty + i * 8) * N + n0 + tx];
    __syncthreads();
    #pragma unroll
    for (int i = 0; i < 4; ++i)
        Wt[(int64_t)(n0 + ty + i * 8) * K + k0 + tx] = f32_to_bf16(t[tx][ty + i * 8]);
}

// ---------------------------------------------------------------------------
// GEMM (R6/R14-proven core): C(MxN) = A(MxK,bf16) @ Bt(NxK,bf16)^T + bias
// MODE 0: C = relu(.) -> bf16 Cb  (epilogue unchanged from R14)
// MODE 1: coupling epilogue via LDS C-transpose (NEW, R15):
//   K-loop's scattered acc is staged into a f32 LDS half-tile (As/Bs are
//   dead), then each thread streams ONE contiguous 64-float row segment:
//   8x ds_read_b128 + 16 dense float4 x-loads + 16 dense float4 y-stores.
//   Replaces 64 scattered 8B x/y accesses per thread (R14 G3: 3.2 TB/s,
//   latency-bound tail ~80us).  Pad 68 f32/row: write = 32 banks x 2 = free;
//   read = uniform 8 lanes/bank (structural minimum for b128).
// 128x128 tile, BK=64, 4 waves. T1 XCD swizzle; T2 chunk-XOR (measured 0
// conflicts); launch_bounds(256,4) ((256,5) spills the acc — R1).
// LDS 34816B -> still 4 blocks/CU (4x34816 < 160KB).
// ---------------------------------------------------------------------------
template<int K, int N, int MODE>
__global__ __launch_bounds__(256, 4)
void gemm_bt(const u16* __restrict__ A, const u16* __restrict__ Bt,
             const float* __restrict__ bias,
             u16* __restrict__ Cb,
             const float* __restrict__ X,
             float* __restrict__ Y) {
    constexpr int BK = 64;
    __shared__ __align__(16) char pool[34816];
    u16* const As = (u16*)pool;              // 16 KB
    u16* const Bs = (u16*)(pool + 16384);    // 16 KB

    const int tid  = threadIdx.x;
    const int lane = tid & 63;
    const int w    = tid >> 6;      // wave 0..3
    const int wr   = w >> 1;        // wave row (0..1)
    const int wc   = w & 1;         // wave col (0..1)

    // T1: XCD swizzle (grids here are all multiples of 8 -> bijective).
    const int nwg = gridDim.x;
    const int cpx = nwg >> 3;
    const int bid = (blockIdx.x & 7) * cpx + (blockIdx.x >> 3);

    constexpr int nbn = N / 128;
    const int bm = bid / nbn;
    const int bn = bid % nbn;
    const int m0 = bm * 128;
    const int n0 = bn * 128;

    f32x4 acc[4][4];
    #pragma unroll
    for (int i = 0; i < 4; ++i)
        #pragma unroll
        for (int j = 0; j < 4; ++j)
            acc[i][j] = f32x4{0.f, 0.f, 0.f, 0.f};

    // staging: wave w stages rows [w*32, w*32+32) in 4 calls of 8 rows each.
    // srow = lane>>3 (0..7): staged row = w*32 + c*8 + srow, so row&7 == srow.
    // T2 write side: source chunk = (lane&7) ^ srow.
    const int srow = lane >> 3;
    const int scol = ((lane & 7) ^ srow) * 8;
    const u16* aptr = A  + (int64_t)(m0 + w * 32 + srow) * K + scol;
    const u16* bptr = Bt + (int64_t)(n0 + w * 32 + srow) * K + scol;

    const int rxor = lane & 7;
    const int q0   = lane >> 4;            // 0..3

    for (int kt = 0; kt < K / BK; ++kt) {
        __syncthreads();   // previous tile fully consumed
        const int koff = kt * BK;
        #pragma unroll
        for (int c = 0; c < 4; ++c) {
            __builtin_amdgcn_global_load_lds(
                (gvoid*)(aptr + koff + c * 8 * K),
                (lvoid*)(&As[(w * 32 + c * 8) * BK]), 16, 0, 0);
            __builtin_amdgcn_global_load_lds(
                (gvoid*)(bptr + koff + c * 8 * K),
                (lvoid*)(&Bs[(w * 32 + c * 8) * BK]), 16, 0, 0);
        }
        __syncthreads();   // staged data visible (compiler drains vmcnt(0))

        #pragma unroll
        for (int kk = 0; kk < 2; ++kk) {
            const int kcol = ((kk * 4 + q0) ^ rxor) * 8;   // T2 read side
            bf16x8 a[4], b[4];
            #pragma unroll
            for (int i = 0; i < 4; ++i)
                a[i] = *reinterpret_cast<const bf16x8*>(
                    &As[(wr * 64 + i * 16 + (lane & 15)) * BK + kcol]);
            #pragma unroll
            for (int j = 0; j < 4; ++j)
                b[j] = *reinterpret_cast<const bf16x8*>(
                    &Bs[(wc * 64 + j * 16 + (lane & 15)) * BK + kcol]);
            #pragma unroll
            for (int i = 0; i < 4; ++i)
                #pragma unroll
                for (int j = 0; j < 4; ++j)
                    acc[i][j] = __builtin_amdgcn_mfma_f32_16x16x32_bf16(
                        a[i], b[j], acc[i][j], 0, 0, 0);
        }
    }

    // C/D layout (m89-verified): col = lane&15, row = (lane>>4)*4 + reg
    const int cl = lane & 15;
    const int rg = (lane >> 4) * 4;

    if (MODE == 0) {
        // ---- relu + bf16 store (R14-identical) ----
        #pragma unroll
        for (int j = 0; j < 4; ++j) {
            const int n  = n0 + wc * 64 + j * 16 + cl;
            const float bv = bias[n];
            #pragma unroll
            for (int i = 0; i < 4; ++i) {
                #pragma unroll
                for (int r = 0; r < 4; ++r) {
                    const int m = m0 + wr * 64 + i * 16 + rg + r;
                    float v = acc[i][j][r] + bv;
                    v = v > 0.f ? v : 0.f;
                    Cb[(int64_t)m * N + n] = f32_to_bf16(v);
                }
            }
        }
    } else {
        // ---- coupling epilogue via LDS C-transpose ----
        constexpr int CP = 68;                 // f32 pitch (16B-aligned rows)
        float* const Cs = (float*)pool;        // 128 x 68 f32 = 34816 B
        #pragma unroll
        for (int jh = 0; jh < 2; ++jh) {
            __syncthreads();   // staging reads / previous half reads done
            // write half: cols c2 = wc*32 + jj*16 + cl  (global n = n0 + wc*64 + jh*32 + jj*16 + cl)
            #pragma unroll
            for (int jj = 0; jj < 2; ++jj) {
                const int j = jh * 2 + jj;
                const float bv = bias[n0 + wc * 64 + jh * 32 + jj * 16 + cl];
                #pragma unroll
                for (int i = 0; i < 4; ++i)
                    #pragma unroll
                    for (int r = 0; r < 4; ++r)
                        Cs[(wr * 64 + i * 16 + rg + r) * CP + wc * 32 + jj * 16 + cl]
                            = acc[i][j][r] + bv;
            }
            __syncthreads();
            // read half: thread -> row tr, 32 c2-cols (= 32 consecutive n)
            const int tr = tid >> 1;           // 0..127
            const int s  = tid & 1;            // which wc-group
            const int nb = n0 + s * 64 + jh * 32;
            const float* crow = Cs + tr * CP + s * 32;
            const int64_t xb = (int64_t)(m0 + tr) * IN_DIM + 2 * nb;
            #pragma unroll
            for (int q = 0; q < 8; ++q) {
                f32x4 t4 = *reinterpret_cast<const f32x4*>(crow + q * 4);
                float4 x0 = *reinterpret_cast<const float4*>(&X[xb + q * 8]);
                float4 x1 = *reinterpret_cast<const float4*>(&X[xb + q * 8 + 4]);
                float4 y0, y1;
                y0.x = x0.x;           y0.y = x0.y + t4[0];
                y0.z = x0.z;           y0.w = x0.w + t4[1];
                y1.x = x1.x;           y1.y = x1.y + t4[2];
                y1.z = x1.z;           y1.w = x1.w + t4[3];
                *reinterpret_cast<float4*>(&Y[xb + q * 8])     = y0;
                *reinterpret_cast<float4*>(&Y[xb + q * 8 + 4]) = y1;
            }
        }
    }
}

// ---------------------------------------------------------------------------
extern "C" void kernel_launch(void* const* d_in, const int* in_sizes, int n_in,
                              void* d_out, int out_size, void* d_ws, size_t ws_size,
                              hipStream_t stream) {
    const float* x  = (const float*)d_in[0];
    const float* W1 = (const float*)d_in[1];
    const float* b1 = (const float*)d_in[2];
    const float* W2 = (const float*)d_in[3];
    const float* b2 = (const float*)d_in[4];
    const float* W3 = (const float*)d_in[5];
    const float* b3 = (const float*)d_in[6];
    float* y = (float*)d_out;

    char* ws = (char*)d_ws;
    // layout: h1 (128MB) | h2 (128MB, first 64MB aliased by xm) | W1t|W2t|W3t
    u16* h1  = (u16*)(ws);
    u16* h2  = (u16*)(ws + 134217728);
    u16* xm  = (u16*)(ws + 134217728);                 // dead before h2 is written
    u16* W1t = (u16*)(ws + 268435456);
    u16* W2t = (u16*)(ws + 268435456 + 1048576);
    u16* W3t = (u16*)(ws + 268435456 + 1048576 + 2097152);

    // 1) prep (even-col extract) + all weight converts, one dispatch
    prep_all<<<32768 + 2048, 256, 0, stream>>>(x, xm, W1, W2, W3, W1t, W2t, W3t);

    // 2) three GEMMs (R6 16x16 core; G3 with LDS-transpose epilogue)
    gemm_bt<MASKED, HIDDEN, 0><<<(BATCH / 128) * (HIDDEN / 128), 256, 0, stream>>>(
        xm, W1t, b1, h1, nullptr, nullptr);
    gemm_bt<HIDDEN, HIDDEN, 0><<<(BATCH / 128) * (HIDDEN / 128), 256, 0, stream>>>(
        h1, W2t, b2, h2, nullptr, nullptr);
    gemm_bt<HIDDEN, IN_DIM - MASKED, 1><<<(BATCH / 128) * ((IN_DIM - MASKED) / 128), 256, 0, stream>>>(
        h2, W3t, b3, nullptr, x, y);
}

// Round 16
// 443.038 us; speedup vs baseline: 1.0744x; 1.0744x over previous
//
#include <hip/hip_runtime.h>
#include <stdint.h>

#define BATCH  65536
#define IN_DIM 1024
#define MASKED 512
#define HIDDEN 1024

typedef unsigned short u16;
typedef __bf16 bf16x8 __attribute__((ext_vector_type(8)));
typedef float  f32x4  __attribute__((ext_vector_type(4)));

typedef __attribute__((address_space(1))) void gvoid;
typedef __attribute__((address_space(3))) void lvoid;

__device__ __forceinline__ u16 f32_to_bf16(float f) {
    union { float f; uint32_t u; } v; v.f = f;
    uint32_t r = v.u + 0x7FFFu + ((v.u >> 16) & 1u);   // round-to-nearest-even
    return (u16)(r >> 16);
}

// ---------------------------------------------------------------------------
// prep + weight-convert merged into ONE dispatch (saves launch gaps).
// blocks [0, 32768):     x (BATCH x IN_DIM f32) -> xm (BATCH x MASKED bf16)
// blocks [32768, 34816): W1/W2/W3 (K x N f32) -> Wt (N x K bf16), 32x32 tiles
// ---------------------------------------------------------------------------
__global__ void prep_all(const float* __restrict__ x, u16* __restrict__ xm,
                         const float* __restrict__ W1, const float* __restrict__ W2,
                         const float* __restrict__ W3,
                         u16* __restrict__ W1t, u16* __restrict__ W2t,
                         u16* __restrict__ W3t) {
    __shared__ float t[32][33];
    int bid = blockIdx.x;
    if (bid < 32768) {
        // ---- prep: even-column extract + bf16 ----
        int idx = bid * blockDim.x + threadIdx.x;
        const float4* xv = reinterpret_cast<const float4*>(x);
        float4 v0 = xv[idx * 2];
        float4 v1 = xv[idx * 2 + 1];
        ushort4 o;
        o.x = f32_to_bf16(v0.x);
        o.y = f32_to_bf16(v0.z);
        o.z = f32_to_bf16(v1.x);
        o.w = f32_to_bf16(v1.z);
        reinterpret_cast<ushort4*>(xm)[idx] = o;
        return;
    }
    bid -= 32768;
    const float* W; u16* Wt; int K, N;
    if (bid < 512)       { W = W1; Wt = W1t; K = 512;  N = 1024; }
    else if (bid < 1536) { W = W2; Wt = W2t; K = 1024; N = 1024; bid -= 512; }
    else                 { W = W3; Wt = W3t; K = 1024; N = 512;  bid -= 1536; }
    const int nbk = K / 32;
    const int bk = bid % nbk;
    const int bn = bid / nbk;
    const int tx = threadIdx.x & 31;
    const int ty = threadIdx.x >> 5;   // 0..7
    const int k0 = bk * 32, n0 = bn * 32;
    #pragma unroll
    for (int i = 0; i < 4; ++i)
        t[ty + i * 8][tx] = W[(int64_t)(k0 + ty + i * 8) * N + n0 + tx];
    __syncthreads();
    #pragma unroll
    for (int i = 0; i < 4; ++i)
        Wt[(int64_t)(n0 + ty + i * 8) * K + k0 + tx] = f32_to_bf16(t[tx][ty + i * 8]);
}

// ---------------------------------------------------------------------------
// GEMM (R6/R14-proven core, best measured total: 435 us):
//   C(MxN) = A(MxK,bf16) @ Bt(NxK,bf16)^T + bias, mfma 16x16x32
// MODE 0: C = relu(.) -> bf16 Cb
// MODE 1: coupling epilogue, R16: per j-group, batch-issue all 16 float2
//   x-loads into registers (16-deep MLP) before the 16 add+stores.  R14's
//   interleaved load->add->store kept only ~4 loads in flight (G3 tail
//   ~80us latency-exposed).  Lane coalescing unchanged (16 lanes x 8B =
//   128B segments — R15 proved per-wave coalescing dominates per-thread
//   streaming).
// 128x128 tile, BK=64, 4 waves. T1 XCD swizzle.
// launch_bounds(256,4) — (256,5) spills the acc (R1).
// T2 chunk-XOR swizzle (measured 0 bank conflicts): LDS slot s of row r
// holds global chunk s^(r&7); XOR applied on the per-lane GLOBAL source
// (DMA stays linear) and on the fragment-read chunk index.
// ---------------------------------------------------------------------------
template<int K, int N, int MODE>
__global__ __launch_bounds__(256, 4)
void gemm_bt(const u16* __restrict__ A, const u16* __restrict__ Bt,
             const float* __restrict__ bias,
             u16* __restrict__ Cb,
             const float* __restrict__ X,
             float* __restrict__ Y) {
    constexpr int BK = 64;
    __shared__ u16 As[128 * BK];
    __shared__ u16 Bs[128 * BK];

    const int tid  = threadIdx.x;
    const int lane = tid & 63;
    const int w    = tid >> 6;      // wave 0..3
    const int wr   = w >> 1;        // wave row (0..1)
    const int wc   = w & 1;         // wave col (0..1)

    // T1: XCD swizzle (grids here are all multiples of 8 -> bijective).
    const int nwg = gridDim.x;
    const int cpx = nwg >> 3;
    const int bid = (blockIdx.x & 7) * cpx + (blockIdx.x >> 3);

    constexpr int nbn = N / 128;
    const int bm = bid / nbn;
    const int bn = bid % nbn;
    const int m0 = bm * 128;
    const int n0 = bn * 128;

    f32x4 acc[4][4];
    #pragma unroll
    for (int i = 0; i < 4; ++i)
        #pragma unroll
        for (int j = 0; j < 4; ++j)
            acc[i][j] = f32x4{0.f, 0.f, 0.f, 0.f};

    // staging: wave w stages rows [w*32, w*32+32) in 4 calls of 8 rows each.
    // srow = lane>>3 (0..7): staged row = w*32 + c*8 + srow, so row&7 == srow.
    // T2 write side: source chunk = (lane&7) ^ srow.
    const int srow = lane >> 3;
    const int scol = ((lane & 7) ^ srow) * 8;
    const u16* aptr = A  + (int64_t)(m0 + w * 32 + srow) * K + scol;
    const u16* bptr = Bt + (int64_t)(n0 + w * 32 + srow) * K + scol;

    const int rxor = lane & 7;
    const int q0   = lane >> 4;            // 0..3

    for (int kt = 0; kt < K / BK; ++kt) {
        __syncthreads();   // previous tile fully consumed
        const int koff = kt * BK;
        #pragma unroll
        for (int c = 0; c < 4; ++c) {
            __builtin_amdgcn_global_load_lds(
                (gvoid*)(aptr + koff + c * 8 * K),
                (lvoid*)(&As[(w * 32 + c * 8) * BK]), 16, 0, 0);
            __builtin_amdgcn_global_load_lds(
                (gvoid*)(bptr + koff + c * 8 * K),
                (lvoid*)(&Bs[(w * 32 + c * 8) * BK]), 16, 0, 0);
        }
        __syncthreads();   // staged data visible (compiler drains vmcnt(0))

        #pragma unroll
        for (int kk = 0; kk < 2; ++kk) {
            const int kcol = ((kk * 4 + q0) ^ rxor) * 8;   // T2 read side
            bf16x8 a[4], b[4];
            #pragma unroll
            for (int i = 0; i < 4; ++i)
                a[i] = *reinterpret_cast<const bf16x8*>(
                    &As[(wr * 64 + i * 16 + (lane & 15)) * BK + kcol]);
            #pragma unroll
            for (int j = 0; j < 4; ++j)
                b[j] = *reinterpret_cast<const bf16x8*>(
                    &Bs[(wc * 64 + j * 16 + (lane & 15)) * BK + kcol]);
            #pragma unroll
            for (int i = 0; i < 4; ++i)
                #pragma unroll
                for (int j = 0; j < 4; ++j)
                    acc[i][j] = __builtin_amdgcn_mfma_f32_16x16x32_bf16(
                        a[i], b[j], acc[i][j], 0, 0, 0);
        }
    }

    // epilogue. C/D layout (m89-verified): col = lane&15, row = (lane>>4)*4 + reg
    const int cl = lane & 15;
    const int rg = (lane >> 4) * 4;
    #pragma unroll
    for (int j = 0; j < 4; ++j) {
        const int n  = n0 + wc * 64 + j * 16 + cl;
        const float bv = bias[n];
        if (MODE == 0) {
            #pragma unroll
            for (int i = 0; i < 4; ++i) {
                #pragma unroll
                for (int r = 0; r < 4; ++r) {
                    const int m = m0 + wr * 64 + i * 16 + rg + r;
                    float v = acc[i][j][r] + bv;
                    v = v > 0.f ? v : 0.f;
                    Cb[(int64_t)m * N + n] = f32_to_bf16(v);
                }
            }
        } else {
            // batch-issue all 16 x loads of this j-group (16-deep MLP),
            // then the 16 add+stores.  xv[] statically indexed (rule #20).
            float2 xv[16];
            #pragma unroll
            for (int i = 0; i < 4; ++i)
                #pragma unroll
                for (int r = 0; r < 4; ++r) {
                    const int m = m0 + wr * 64 + i * 16 + rg + r;
                    xv[i * 4 + r] = *reinterpret_cast<const float2*>(
                        &X[(int64_t)m * IN_DIM + 2 * n]);
                }
            #pragma unroll
            for (int i = 0; i < 4; ++i)
                #pragma unroll
                for (int r = 0; r < 4; ++r) {
                    const int m = m0 + wr * 64 + i * 16 + rg + r;
                    const float v = acc[i][j][r] + bv;
                    float2 o;
                    o.x = xv[i * 4 + r].x;          // even column: exact copy
                    o.y = xv[i * 4 + r].y + v;      // odd column: x + translation
                    *reinterpret_cast<float2*>(&Y[(int64_t)m * IN_DIM + 2 * n]) = o;
                }
        }
    }
}

// ---------------------------------------------------------------------------
extern "C" void kernel_launch(void* const* d_in, const int* in_sizes, int n_in,
                              void* d_out, int out_size, void* d_ws, size_t ws_size,
                              hipStream_t stream) {
    const float* x  = (const float*)d_in[0];
    const float* W1 = (const float*)d_in[1];
    const float* b1 = (const float*)d_in[2];
    const float* W2 = (const float*)d_in[3];
    const float* b2 = (const float*)d_in[4];
    const float* W3 = (const float*)d_in[5];
    const float* b3 = (const float*)d_in[6];
    float* y = (float*)d_out;

    char* ws = (char*)d_ws;
    // layout: h1 (128MB) | h2 (128MB, first 64MB aliased by xm) | W1t|W2t|W3t
    u16* h1  = (u16*)(ws);
    u16* h2  = (u16*)(ws + 134217728);
    u16* xm  = (u16*)(ws + 134217728);                 // dead before h2 is written
    u16* W1t = (u16*)(ws + 268435456);
    u16* W2t = (u16*)(ws + 268435456 + 1048576);
    u16* W3t = (u16*)(ws + 268435456 + 1048576 + 2097152);

    // 1) prep (even-col extract) + all weight converts, one dispatch
    prep_all<<<32768 + 2048, 256, 0, stream>>>(x, xm, W1, W2, W3, W1t, W2t, W3t);

    // 2) three GEMMs (R14 16x16 core; G3 with batched-load epilogue)
    gemm_bt<MASKED, HIDDEN, 0><<<(BATCH / 128) * (HIDDEN / 128), 256, 0, stream>>>(
        xm, W1t, b1, h1, nullptr, nullptr);
    gemm_bt<HIDDEN, HIDDEN, 0><<<(BATCH / 128) * (HIDDEN / 128), 256, 0, stream>>>(
        h1, W2t, b2, h2, nullptr, nullptr);
    gemm_bt<HIDDEN, IN_DIM - MASKED, 1><<<(BATCH / 128) * ((IN_DIM - MASKED) / 128), 256, 0, stream>>>(
        h2, W3t, b3, nullptr, x, y);
}

// Round 17
// 436.256 us; speedup vs baseline: 1.0911x; 1.0155x over previous
//
#include <hip/hip_runtime.h>
#include <stdint.h>

#define BATCH  65536
#define IN_DIM 1024
#define MASKED 512
#define HIDDEN 1024

typedef unsigned short u16;
typedef __bf16 bf16x8 __attribute__((ext_vector_type(8)));
typedef float  f32x4  __attribute__((ext_vector_type(4)));

typedef __attribute__((address_space(1))) void gvoid;
typedef __attribute__((address_space(3))) void lvoid;

__device__ __forceinline__ u16 f32_to_bf16(float f) {
    union { float f; uint32_t u; } v; v.f = f;
    uint32_t r = v.u + 0x7FFFu + ((v.u >> 16) & 1u);   // round-to-nearest-even
    return (u16)(r >> 16);
}

// ---------------------------------------------------------------------------
// prep + weight-convert merged into ONE dispatch (saves launch gaps).
// blocks [0, 32768):     x (BATCH x IN_DIM f32) -> xm (BATCH x MASKED bf16)
// blocks [32768, 34816): W1/W2/W3 (K x N f32) -> Wt (N x K bf16), 32x32 tiles
// ---------------------------------------------------------------------------
__global__ void prep_all(const float* __restrict__ x, u16* __restrict__ xm,
                         const float* __restrict__ W1, const float* __restrict__ W2,
                         const float* __restrict__ W3,
                         u16* __restrict__ W1t, u16* __restrict__ W2t,
                         u16* __restrict__ W3t) {
    __shared__ float t[32][33];
    int bid = blockIdx.x;
    if (bid < 32768) {
        // ---- prep: even-column extract + bf16 ----
        int idx = bid * blockDim.x + threadIdx.x;
        const float4* xv = reinterpret_cast<const float4*>(x);
        float4 v0 = xv[idx * 2];
        float4 v1 = xv[idx * 2 + 1];
        ushort4 o;
        o.x = f32_to_bf16(v0.x);
        o.y = f32_to_bf16(v0.z);
        o.z = f32_to_bf16(v1.x);
        o.w = f32_to_bf16(v1.z);
        reinterpret_cast<ushort4*>(xm)[idx] = o;
        return;
    }
    bid -= 32768;
    const float* W; u16* Wt; int K, N;
    if (bid < 512)       { W = W1; Wt = W1t; K = 512;  N = 1024; }
    else if (bid < 1536) { W = W2; Wt = W2t; K = 1024; N = 1024; bid -= 512; }
    else                 { W = W3; Wt = W3t; K = 1024; N = 512;  bid -= 1536; }
    const int nbk = K / 32;
    const int bk = bid % nbk;
    const int bn = bid / nbk;
    const int tx = threadIdx.x & 31;
    const int ty = threadIdx.x >> 5;   // 0..7
    const int k0 = bk * 32, n0 = bn * 32;
    #pragma unroll
    for (int i = 0; i < 4; ++i)
        t[ty + i * 8][tx] = W[(int64_t)(k0 + ty + i * 8) * N + n0 + tx];
    __syncthreads();
    #pragma unroll
    for (int i = 0; i < 4; ++i)
        Wt[(int64_t)(n0 + ty + i * 8) * K + k0 + tx] = f32_to_bf16(t[tx][ty + i * 8]);
}

// ---------------------------------------------------------------------------
// GEMM (R6/R14-proven core — best measured total: 435 us):
//   C(MxN) = A(MxK,bf16) @ Bt(NxK,bf16)^T + bias, mfma 16x16x32
// MODE 0: C = relu(.) -> bf16 Cb
// MODE 1: coupling epilogue: y[m][2n] = x[m][2n]; y[m][2n+1] = x[m][2n+1] + t
//   (simple interleaved float2 form; 16 lanes x 8B = 128B coalesced segments.
//    Epilogue measured at ~6.5 TB/s = HBM ceiling — R15 LDS-transpose and
//    R16 batched-load variants were both null/negative.)
// 128x128 tile, BK=64, 256 thr (4 waves 2x2). T1 XCD swizzle.
// launch_bounds(256,4) — (256,5) spills the acc (R1: VGPR 48, +900MB scratch).
//
// T2 chunk-XOR swizzle (measured 0 bank conflicts; 5.03e7 -> 0, G2 −23us):
//   LDS slot s of row r holds global 16B-chunk s^(r&7).  Write side: XOR
//   applied to the per-lane GLOBAL source address (DMA writes stay linear,
//   within the row's 128B -> coalescing intact).  Read side: fragment chunk
//   q = kk*4+(lane>>4) read from slot q^(lane&7) (fragment rows have
//   row&7 == lane&7).  Per 16-lane quarter: 8 bank-groups x 2 lanes = free.
// ---------------------------------------------------------------------------
template<int K, int N, int MODE>
__global__ __launch_bounds__(256, 4)
void gemm_bt(const u16* __restrict__ A, const u16* __restrict__ Bt,
             const float* __restrict__ bias,
             u16* __restrict__ Cb,
             const float* __restrict__ X,
             float* __restrict__ Y) {
    constexpr int BK = 64;
    __shared__ u16 As[128 * BK];
    __shared__ u16 Bs[128 * BK];

    const int tid  = threadIdx.x;
    const int lane = tid & 63;
    const int w    = tid >> 6;      // wave 0..3
    const int wr   = w >> 1;        // wave row (0..1)
    const int wc   = w & 1;         // wave col (0..1)

    // T1: XCD swizzle (grids here are all multiples of 8 -> bijective).
    const int nwg = gridDim.x;
    const int cpx = nwg >> 3;
    const int bid = (blockIdx.x & 7) * cpx + (blockIdx.x >> 3);

    constexpr int nbn = N / 128;
    const int bm = bid / nbn;
    const int bn = bid % nbn;
    const int m0 = bm * 128;
    const int n0 = bn * 128;

    f32x4 acc[4][4];
    #pragma unroll
    for (int i = 0; i < 4; ++i)
        #pragma unroll
        for (int j = 0; j < 4; ++j)
            acc[i][j] = f32x4{0.f, 0.f, 0.f, 0.f};

    // staging: wave w stages rows [w*32, w*32+32) in 4 calls of 8 rows each.
    // srow = lane>>3 (0..7): staged row = w*32 + c*8 + srow, so row&7 == srow.
    // T2 write side: source chunk = (lane&7) ^ srow.
    const int srow = lane >> 3;
    const int scol = ((lane & 7) ^ srow) * 8;
    const u16* aptr = A  + (int64_t)(m0 + w * 32 + srow) * K + scol;
    const u16* bptr = Bt + (int64_t)(n0 + w * 32 + srow) * K + scol;

    const int rxor = lane & 7;
    const int q0   = lane >> 4;            // 0..3

    for (int kt = 0; kt < K / BK; ++kt) {
        __syncthreads();   // previous tile fully consumed
        const int koff = kt * BK;
        #pragma unroll
        for (int c = 0; c < 4; ++c) {
            __builtin_amdgcn_global_load_lds(
                (gvoid*)(aptr + koff + c * 8 * K),
                (lvoid*)(&As[(w * 32 + c * 8) * BK]), 16, 0, 0);
            __builtin_amdgcn_global_load_lds(
                (gvoid*)(bptr + koff + c * 8 * K),
                (lvoid*)(&Bs[(w * 32 + c * 8) * BK]), 16, 0, 0);
        }
        __syncthreads();   // staged data visible (compiler drains vmcnt(0))

        #pragma unroll
        for (int kk = 0; kk < 2; ++kk) {
            const int kcol = ((kk * 4 + q0) ^ rxor) * 8;   // T2 read side
            bf16x8 a[4], b[4];
            #pragma unroll
            for (int i = 0; i < 4; ++i)
                a[i] = *reinterpret_cast<const bf16x8*>(
                    &As[(wr * 64 + i * 16 + (lane & 15)) * BK + kcol]);
            #pragma unroll
            for (int j = 0; j < 4; ++j)
                b[j] = *reinterpret_cast<const bf16x8*>(
                    &Bs[(wc * 64 + j * 16 + (lane & 15)) * BK + kcol]);
            #pragma unroll
            for (int i = 0; i < 4; ++i)
                #pragma unroll
                for (int j = 0; j < 4; ++j)
                    acc[i][j] = __builtin_amdgcn_mfma_f32_16x16x32_bf16(
                        a[i], b[j], acc[i][j], 0, 0, 0);
        }
    }

    // epilogue. C/D layout (m89-verified): col = lane&15, row = (lane>>4)*4 + reg
    const int cl = lane & 15;
    const int rg = (lane >> 4) * 4;
    #pragma unroll
    for (int j = 0; j < 4; ++j) {
        const int n  = n0 + wc * 64 + j * 16 + cl;
        const float bv = bias[n];
        #pragma unroll
        for (int i = 0; i < 4; ++i) {
            #pragma unroll
            for (int r = 0; r < 4; ++r) {
                const int m = m0 + wr * 64 + i * 16 + rg + r;
                float v = acc[i][j][r] + bv;
                if (MODE == 0) {
                    v = v > 0.f ? v : 0.f;
                    Cb[(int64_t)m * N + n] = f32_to_bf16(v);
                } else {
                    const int64_t p = (int64_t)m * IN_DIM + 2 * n;
                    float2 xv = *reinterpret_cast<const float2*>(&X[p]);
                    float2 o;
                    o.x = xv.x;          // even column: exact copy
                    o.y = xv.y + v;      // odd column: x + translation
                    *reinterpret_cast<float2*>(&Y[p]) = o;
                }
            }
        }
    }
}

// ---------------------------------------------------------------------------
extern "C" void kernel_launch(void* const* d_in, const int* in_sizes, int n_in,
                              void* d_out, int out_size, void* d_ws, size_t ws_size,
                              hipStream_t stream) {
    const float* x  = (const float*)d_in[0];
    const float* W1 = (const float*)d_in[1];
    const float* b1 = (const float*)d_in[2];
    const float* W2 = (const float*)d_in[3];
    const float* b2 = (const float*)d_in[4];
    const float* W3 = (const float*)d_in[5];
    const float* b3 = (const float*)d_in[6];
    float* y = (float*)d_out;

    char* ws = (char*)d_ws;
    // layout: h1 (128MB) | h2 (128MB, first 64MB aliased by xm) | W1t|W2t|W3t
    u16* h1  = (u16*)(ws);
    u16* h2  = (u16*)(ws + 134217728);
    u16* xm  = (u16*)(ws + 134217728);                 // dead before h2 is written
    u16* W1t = (u16*)(ws + 268435456);
    u16* W2t = (u16*)(ws + 268435456 + 1048576);
    u16* W3t = (u16*)(ws + 268435456 + 1048576 + 2097152);

    // 1) prep (even-col extract) + all weight converts, one dispatch
    prep_all<<<32768 + 2048, 256, 0, stream>>>(x, xm, W1, W2, W3, W1t, W2t, W3t);

    // 2) three GEMMs (R6 16x16 core)
    gemm_bt<MASKED, HIDDEN, 0><<<(BATCH / 128) * (HIDDEN / 128), 256, 0, stream>>>(
        xm, W1t, b1, h1, nullptr, nullptr);
    gemm_bt<HIDDEN, HIDDEN, 0><<<(BATCH / 128) * (HIDDEN / 128), 256, 0, stream>>>(
        h1, W2t, b2, h2, nullptr, nullptr);
    gemm_bt<HIDDEN, IN_DIM - MASKED, 1><<<(BATCH / 128) * ((IN_DIM - MASKED) / 128), 256, 0, stream>>>(
        h2, W3t, b3, nullptr, x, y);
}